// Round 10
// baseline (1073.769 us; speedup 1.0000x reference)
//
#include <hip/hip_runtime.h>

typedef unsigned int u32;
typedef unsigned long long u64;
typedef unsigned short u16;

#define NTOT   67108864u    // 8192*8192 = 2^26
#define T0P    7543296u     // candidate threshold = PBASE*512; true cutoff 7549747 +- 324 (20 sigma)
#define PBASE  14733u       // T0P >> 9
#define NSUP   1651u        // supers of 512 fine bins, covering [T0P, 2^23)
#define NWSEG  4096u        // per-wave segments (1024 pass1 blocks x 4 waves)
#define WCAP   2176u        // per-wave cap: mean 1487, sigma 36.8 -> +18.7 sigma
#define RCAP   4352u        // per-super cap: mean 3689, sigma 61 -> +10.9 sigma
#define KSPLIT 4            // gemm2 split-K: grid 512 = 2 blocks/CU, no residency tail
#define RBLK   512u         // k_route blocks (2 blocks/CU)
#define SEGPB  8            // segs per route block (RBLK*SEGPB = NWSEG)
#define FLIPCAP 6291456u    // flip list cap (nflip ~= 6.04M, sigma ~245)
#define NBKT   1024u        // flip buckets by v>>16 (128 KB wbf window)
#define BCAP1  8192u        // per-bucket cap: mean 5898, sigma 76.6 -> +30 sigma

struct Scalars {
  double sumW;
  double sumW2;
  u64 npruned;
  u64 nflip;
  float stdf;
  float pad;
};

// ---- ws layout (bytes) ----
#define OFF_COLSUM 0ull          // gcur/colsum: 2048 u32 = 8192
#define OFF_SBASE  8192ull       // 2048 u32 -> ends 16384
#define OFF_SC     16384ull      // 128 B
#define OFF_SEGCNT 16512ull      // 4096 u32 -> ends 32896
#define OFF_XBF    33024ull      // 4,194,304 -> ends 4,227,328
#define OFF_SEGS   4227328ull    // 35,651,584 -> ends 39,878,912
#define OFF_ROUTED 39878912ull   // 2048*4352*4 = 35,651,584 -> ends 75,530,496
#define OFF_WBF    75530496ull   // bf16 W copy: 134,217,728 -> ends 209,748,224
#define WS_NEED_WBF 209748224ull
// tier3: flip-sort buffers after wbf
#define OFF_FLIPF  209748224ull  // FLIPCAP u64 = 50,331,648 -> ends 260,079,872
#define OFF_FB1    260079872ull  // NBKT*BCAP1 u64 = 67,108,864 -> ends 327,188,736
#define OFF_BCUR   327188736ull  // 1024 u32 = 4096
#define WS_NEED_T3 327192832ull
// gemm2 partials REUSE segs+routed (dead after rank/apply): 4 x 8 MB = 32 MB ok
#define OFF_OUTP   OFF_SEGS

// JAX Threefry-2x32, 20 rounds — verified vs known-answer vector
__host__ __device__ inline void tf2x32(u32 k0, u32 k1, u32 x0, u32 x1, u32& y0, u32& y1) {
  u32 ks2 = k0 ^ k1 ^ 0x1BD11BDAu;
  x0 += k0; x1 += k1;
#define TFR(r) { x0 += x1; x1 = (x1 << (r)) | (x1 >> (32 - (r))); x1 ^= x0; }
  TFR(13) TFR(15) TFR(26) TFR(6)  x0 += k1;  x1 += ks2 + 1u;
  TFR(17) TFR(29) TFR(16) TFR(24) x0 += ks2; x1 += k0 + 2u;
  TFR(13) TFR(15) TFR(26) TFR(6)  x0 += k0;  x1 += k1 + 3u;
  TFR(17) TFR(29) TFR(16) TFR(24) x0 += k1;  x1 += ks2 + 4u;
  TFR(13) TFR(15) TFR(26) TFR(6)  x0 += ks2; x1 += k0 + 5u;
#undef TFR
  y0 = x0; y1 = x1;
}

// Partitionable-mode bits for element i: counter (0, i), bits = y0 ^ y1
__device__ inline u32 jax_bits32(u32 k0, u32 k1, u32 i) {
  u32 y0, y1; tf2x32(k0, k1, 0u, i, y0, y1);
  return y0 ^ y1;
}

__device__ inline u16 f2bf(float f) {
  union { float f; u32 u; } c; c.f = f;
  u32 r = ((c.u >> 16) & 1u) + 0x7FFFu;   // RNE
  return (u16)((c.u + r) >> 16);
}

// XLA ErfInv (f32, Giles)
__device__ inline float erfinv32(float x) {
  float w = -log1pf(-x * x);
  float p;
  if (w < 5.0f) {
    w -= 2.5f;
    p = 2.81022636e-08f;
    p = fmaf(p, w, 3.43273939e-07f);
    p = fmaf(p, w, -3.5233877e-06f);
    p = fmaf(p, w, -4.39150654e-06f);
    p = fmaf(p, w, 0.00021858087f);
    p = fmaf(p, w, -0.00125372503f);
    p = fmaf(p, w, -0.00417768164f);
    p = fmaf(p, w, 0.246640727f);
    p = fmaf(p, w, 1.50140941f);
  } else {
    w = sqrtf(w) - 3.0f;
    p = -0.000200214257f;
    p = fmaf(p, w, 0.000100950558f);
    p = fmaf(p, w, 0.00134934322f);
    p = fmaf(p, w, -0.00367342844f);
    p = fmaf(p, w, 0.00573950773f);
    p = fmaf(p, w, -0.0076224613f);
    p = fmaf(p, w, 0.00943887047f);
    p = fmaf(p, w, 1.00167406f);
    p = fmaf(p, w, 2.83297682f);
  }
  return p * x;
}

// Fused pass1 + wconv + xconv heterogeneous grid (R5/R9 structure, ~308us).
__global__ __launch_bounds__(256) void k_pass1w(const float* __restrict__ W,
                                                u16* __restrict__ wbf,
                                                const float* __restrict__ x,
                                                u16* __restrict__ xbf,
                                                Scalars* sc, u32* segcnt, u32* segs,
                                                u32 uk0, u32 uk1, u32 dowbf) {
  u32 t = threadIdx.x;
  u32 bid = blockIdx.x;
  if (bid < 1024u) {
    u32 gid = bid * 256 + t;
    u32 lane = t & 63;
    u32 wid = gid >> 6;
    u32* wseg = segs + (u64)wid * WCAP;
    u32 wbase = 0;                     // wave-uniform cursor, kept in registers
    float sf = 0.f, sf2 = 0.f; u32 cnt = 0;
    const u32 stride4 = 1024u * 256u * 4u;
    for (u32 b4 = gid * 4; b4 < NTOT; b4 += stride4) {
      float4 w4 = *(const float4*)(W + b4);
      u32 sb0 = jax_bits32(uk0, uk1, b4 + 0) >> 9;   // 4 independent chains
      u32 sb1 = jax_bits32(uk0, uk1, b4 + 1) >> 9;
      u32 sb2 = jax_bits32(uk0, uk1, b4 + 2) >> 9;
      u32 sb3 = jax_bits32(uk0, uk1, b4 + 3) >> 9;
      float we[4] = {w4.x, w4.y, w4.z, w4.w};
      u32 sbv[4] = {sb0, sb1, sb2, sb3};
      u32 cand[4]; u32 nc = 0;
#pragma unroll
      for (int e = 0; e < 4; e++) {
        float w = we[e];
        sf += w;
        sf2 = fmaf(w, w, sf2);
        bool pr = (w == 0.0f);
        cnt += pr ? 1u : 0u;
        if (pr && sbv[e] >= T0P) { cand[nc] = b4 + e; nc++; }
      }
      u32 inc = nc;                    // wave inclusive scan of per-lane counts
#pragma unroll
      for (int o = 1; o < 64; o <<= 1) { u32 v = (u32)__shfl_up((int)inc, o); if (lane >= (u32)o) inc += v; }
      u32 tot = (u32)__shfl((int)inc, 63);
      u32 pos = wbase + inc - nc;
      for (u32 k2 = 0; k2 < nc; k2++)
        if (pos + k2 < WCAP) wseg[pos + k2] = cand[k2];
      wbase += tot;
    }
    double s = (double)sf, s2 = (double)sf2;
    for (int o = 32; o > 0; o >>= 1) {
      s += __shfl_down(s, o); s2 += __shfl_down(s2, o); cnt += __shfl_down(cnt, o);
    }
    if (lane == 0) {
      atomicAdd(&sc->sumW, s);
      atomicAdd(&sc->sumW2, s2);
      atomicAdd(&sc->npruned, (u64)cnt);
      segcnt[wid] = (wbase > WCAP) ? WCAP : wbase;
    }
  } else if (bid < 1984u) {
    if (!dowbf) return;
    u32 i0 = (bid - 1024u) * 256 + t;
    const u32 stride = 960u * 256u;
    for (u32 g = i0; g < NTOT / 8u; g += stride) {
      const float4* p = (const float4*)(W + (u64)g * 8);
      float4 a = p[0], b = p[1];
      uint4 o;
      o.x = (u32)f2bf(a.x) | ((u32)f2bf(a.y) << 16);
      o.y = (u32)f2bf(a.z) | ((u32)f2bf(a.w) << 16);
      o.z = (u32)f2bf(b.x) | ((u32)f2bf(b.y) << 16);
      o.w = (u32)f2bf(b.z) | ((u32)f2bf(b.w) << 16);
      *(uint4*)(wbf + (u64)g * 8) = o;
    }
  } else {
    u32 i0 = (bid - 1984u) * 256 + t;
    const u32 stride = 64u * 256u;
    for (u32 g = i0; g < 524288u; g += stride) {
      float4 v = ((const float4*)x)[g];
      ushort4 o; o.x = f2bf(v.x); o.y = f2bf(v.y); o.z = f2bf(v.z); o.w = f2bf(v.w);
      ((ushort4*)xbf)[g] = o;
    }
  }
}

// Single-pass route: LDS count -> global reserve -> scatter into fixed-stride
// routed[sup*RCAP] (R9, verified).
__global__ __launch_bounds__(256) void k_route(const u32* __restrict__ segs,
                                               const u32* __restrict__ segcnt,
                                               u32* gcur, u32* routed,
                                               u32 uk0, u32 uk1) {
  __shared__ u32 lhist[2048];
  __shared__ u32 lbase[2048];
  u32 t = threadIdx.x;
  for (u32 j = t; j < 2048; j += 256) lhist[j] = 0;
  __syncthreads();
#pragma unroll 1
  for (int sg = 0; sg < SEGPB; sg++) {
    u32 wid = blockIdx.x * SEGPB + sg;
    u32 n = segcnt[wid]; if (n > WCAP) n = WCAP;
    const u32* sp = segs + (u64)wid * WCAP;
    for (u32 i = t; i < n; i += 256)
      atomicAdd(&lhist[(jax_bits32(uk0, uk1, sp[i]) >> 18) - PBASE], 1u);
  }
  __syncthreads();
  for (u32 j = t; j < 2048; j += 256) {
    u32 c = lhist[j];
    lbase[j] = c ? atomicAdd(&gcur[j], c) : 0u;
    lhist[j] = 0;
  }
  __syncthreads();
#pragma unroll 1
  for (int sg = 0; sg < SEGPB; sg++) {
    u32 wid = blockIdx.x * SEGPB + sg;
    u32 n = segcnt[wid]; if (n > WCAP) n = WCAP;
    const u32* sp = segs + (u64)wid * WCAP;
    for (u32 i = t; i < n; i += 256) {
      u32 idx = sp[i];
      u32 sup = (jax_bits32(uk0, uk1, idx) >> 18) - PBASE;
      u32 pos = lbase[sup] + atomicAdd(&lhist[sup], 1u);
      if (pos < RCAP) routed[(u64)sup * RCAP + pos] = idx;
    }
  }
}

// Scalars + 2048-wide suffix-exclusive scan (sbase = rank base per super).
__global__ __launch_bounds__(256) void k_scan(const u32* __restrict__ colsum, Scalars* sc,
                                              u32* sbase) {
  __shared__ u32 h[2048];
  __shared__ u32 wtmp[4];
  u32 t = threadIdx.x, lane = t & 63, wv = t >> 6;
  for (u32 j = t; j < 2048; j += 256) h[j] = colsum[j];
  __syncthreads();
  u32 a[8]; u32 s8 = 0;
#pragma unroll
  for (int k = 0; k < 8; k++) { a[k] = h[2047 - (t * 8 + k)]; s8 += a[k]; }
  u32 inc = s8;
#pragma unroll
  for (int o = 1; o < 64; o <<= 1) { u32 v = (u32)__shfl_up((int)inc, o); if (lane >= (u32)o) inc += v; }
  if (lane == 63) wtmp[wv] = inc;
  __syncthreads();
  u32 woff = 0; for (u32 w = 0; w < wv; w++) woff += wtmp[w];
  u32 base = woff + inc - s8;
#pragma unroll
  for (int k = 0; k < 8; k++) { sbase[2047 - (t * 8 + k)] = base; base += a[k]; }
  if (t == 0) {
    double nk = (double)NTOT - (double)sc->npruned;
    double mean = sc->sumW / nk;
    double var = (sc->sumW2 - 2.0 * mean * sc->sumW + nk * mean * mean) / (nk - 1.0);
    sc->stdf = (float)sqrt(var);
    u64 nfi = (u64)(0.1 * (double)sc->npruned);
    if (nfi < 1) nfi = 1;
    sc->nflip = nfi;
  }
}

// 512-bin suffix-exclusive scan (256 threads, 2 bins each)
__device__ inline void suf512(const u32* cnt, u32* suf, u32* wtmp) {
  u32 t = threadIdx.x, lane = t & 63, wv = t >> 6;
  u32 a0 = cnt[511 - t * 2], a1 = cnt[510 - t * 2];
  u32 s = a0 + a1;
  u32 inc = s;
#pragma unroll
  for (int o = 1; o < 64; o <<= 1) { u32 v = (u32)__shfl_up((int)inc, o); if (lane >= (u32)o) inc += v; }
  if (lane == 63) wtmp[wv] = inc;
  __syncthreads();
  u32 woff = 0;
  for (u32 w = 0; w < wv; w++) woff += wtmp[w];
  u32 base = woff + inc - s;
  suf[511 - t * 2] = base;
  suf[510 - t * 2] = base + a0;
  __syncthreads();
}

// Rank. MODE 2: rank-indexed append to flipflat (sequential writes; scatter
// moves to k_part/k_apply). MODE 1: direct bf16 scatter. MODE 0: fp32 W.
template<int MODE>
__global__ __launch_bounds__(256) void k_rank(float* __restrict__ W,
                                              u16* __restrict__ wbf,
                                              u64* __restrict__ flipflat,
                                              const u32* __restrict__ colsum,
                                              const u32* __restrict__ sbase,
                                              const u32* __restrict__ routed,
                                              const Scalars* __restrict__ sc,
                                              u32 uk0, u32 uk1, u32 vk0, u32 vk1) {
  u32 p = blockIdx.x;
  u32 n = colsum[p]; if (n == 0) return;
  if (n > RCAP) n = RCAP;
  u64 nflip = sc->nflip;
  u32 rbase = sbase[p];
  if ((u64)rbase >= nflip) return;
  __shared__ u32 sIdx[RCAP];
  __shared__ u16 sFine[RCAP];
  __shared__ u32 pIdx[RCAP];
  __shared__ u32 hist[512], gbase[512], cur[512], wtmp[4];
  u32 t = threadIdx.x;
  for (u32 j = t; j < 512; j += 256) hist[j] = 0;
  __syncthreads();
  const u32* src = routed + (u64)p * RCAP;
  for (u32 i = t; i < n; i += 256) {
    u32 idx = src[i];
    u32 f = (jax_bits32(uk0, uk1, idx) >> 9) & 511u;
    sIdx[i] = idx;
    sFine[i] = (u16)f;
    atomicAdd(&hist[f], 1u);
  }
  __syncthreads();
  suf512(hist, gbase, wtmp);         // gbase[f] = # members with fine > f
  for (u32 j = t; j < 512; j += 256) cur[j] = gbase[j];
  __syncthreads();
  for (u32 i = t; i < n; i += 256) {
    u32 pos = atomicAdd(&cur[sFine[i]], 1u);
    pIdx[pos] = sIdx[i];
  }
  __syncthreads();
  float stdf = sc->stdf;
  for (u32 i = t; i < n; i += 256) {
    u32 f = sFine[i];
    u32 g0 = gbase[f], g1 = g0 + hist[f];
    u32 v = sIdx[i];
    u32 ord = 0;
    for (u32 q = g0; q < g1; q++) ord += (pIdx[q] < v) ? 1u : 0u;
    u64 rank = (u64)rbase + g0 + ord;
    if (rank >= nflip) continue;
    u32 bits = jax_bits32(vk0, vk1, (u32)rank);
    union { u32 u; float fl; } cv; cv.u = 0x3F800000u | (bits >> 9);
    float fu = cv.fl - 1.0f;               // uniform [0,1)
    const float lo = -0.99999994f;         // nextafter(-1,0); (1-lo) rounds to 2.0f
    float u2 = fmaxf(lo, fu * 2.0f + lo);  // uniform [lo, 1)
    float nrm = 1.41421354f * erfinv32(u2);
    float val = (nrm * stdf) * 0.1f;
    if (MODE == 2) {
      if (rank < (u64)FLIPCAP) flipflat[rank] = ((u64)v << 16) | (u64)f2bf(val);
    } else if (MODE == 1) {
      wbf[v] = f2bf(val);
    } else {
      W[v] = val;
    }
  }
}

// Partition flipflat into 1024 buckets by v>>16 (pk>>32). Chunked-LDS sort so
// ALL global writes are coalesced runs (fixes R6's uncoalesced bucket scatter).
__global__ __launch_bounds__(256) void k_part(const u64* __restrict__ flipflat,
                                              const Scalars* __restrict__ sc,
                                              u64* __restrict__ fb1,
                                              u32* __restrict__ bcur) {
  __shared__ u64 buf[4096];
  __shared__ u32 hist[1024], pref[1024], base_[1024], cnt2[1024], wtmp[4];
  u32 t = threadIdx.x, lane = t & 63, wv = t >> 6;
  u32 nf = (u32)sc->nflip; if (nf > FLIPCAP) nf = FLIPCAP;
  u32 per = (nf + 255u) / 256u;
  u32 lo = blockIdx.x * per;
  u32 hi = lo + per; if (hi > nf) hi = nf;
  for (u32 c = lo; c < hi; c += 4096u) {
    u32 m = hi - c; if (m > 4096u) m = 4096u;
    for (u32 j = t; j < 1024; j += 256) { hist[j] = 0; cnt2[j] = 0; }
    __syncthreads();
    u64 it[16];
#pragma unroll
    for (int k = 0; k < 16; k++) {
      u32 i = c + (u32)k * 256u + t;
      if (i < c + m) { it[k] = flipflat[i]; atomicAdd(&hist[(u32)(it[k] >> 32) & 1023u], 1u); }
    }
    __syncthreads();
    {  // exclusive prefix of hist[1024], 4 bins/thread
      u32 a4[4]; u32 s4 = 0;
#pragma unroll
      for (int k = 0; k < 4; k++) { a4[k] = hist[t * 4 + k]; s4 += a4[k]; }
      u32 inc = s4;
#pragma unroll
      for (int o = 1; o < 64; o <<= 1) { u32 v = (u32)__shfl_up((int)inc, o); if (lane >= (u32)o) inc += v; }
      if (lane == 63) wtmp[wv] = inc;
      __syncthreads();
      u32 woff = 0; for (u32 w = 0; w < wv; w++) woff += wtmp[w];
      u32 b = woff + inc - s4;
#pragma unroll
      for (int k = 0; k < 4; k++) { pref[t * 4 + k] = b; b += a4[k]; }
    }
    for (u32 j = t; j < 1024; j += 256) {
      u32 cc = hist[j];
      base_[j] = cc ? atomicAdd(&bcur[j], cc) : 0u;
    }
    __syncthreads();
#pragma unroll
    for (int k = 0; k < 16; k++) {
      u32 i = c + (u32)k * 256u + t;
      if (i < c + m) {
        u32 b = (u32)(it[k] >> 32) & 1023u;
        u32 p = pref[b] + atomicAdd(&cnt2[b], 1u);
        buf[p] = it[k];
      }
    }
    __syncthreads();
    for (u32 j = t; j < m; j += 256) {     // bucket-sorted -> coalesced runs
      u64 pk = buf[j];
      u32 b = (u32)(pk >> 32) & 1023u;
      u32 pos = base_[b] + (j - pref[b]);
      if (pos < BCAP1) fb1[(u64)b * BCAP1 + pos] = pk;
    }
    __syncthreads();
  }
}

// Apply: one block per bucket (128 KB wbf window). Each 4K chunk is LDS-sorted
// by v bits 15..8 (256-elem sub-windows) then written in ascending-address
// order -> a line's ~3 flips land in adjacent iterations -> L2 write-combine.
__global__ __launch_bounds__(256) void k_apply(const u64* __restrict__ fb1,
                                               const u32* __restrict__ bcur,
                                               u16* __restrict__ wbf) {
  __shared__ u64 buf[4096];
  __shared__ u32 hist[256], pref[256], cnt2[256], wtmp[4];
  u32 t = threadIdx.x, lane = t & 63, wv = t >> 6;
  u32 b = blockIdx.x;
  u32 n = bcur[b]; if (n > BCAP1) n = BCAP1;
  const u64* src = fb1 + (u64)b * BCAP1;
  for (u32 c = 0; c < n; c += 4096u) {
    u32 m = n - c; if (m > 4096u) m = 4096u;
    hist[t] = 0; cnt2[t] = 0;
    __syncthreads();
    u64 it[16];
#pragma unroll
    for (int k = 0; k < 16; k++) {
      u32 i = c + (u32)k * 256u + t;
      if (i < c + m) { it[k] = src[i]; atomicAdd(&hist[(u32)(it[k] >> 24) & 255u], 1u); }
    }
    __syncthreads();
    {  // exclusive prefix of hist[256], 1 bin/thread
      u32 v0 = hist[t];
      u32 inc = v0;
#pragma unroll
      for (int o = 1; o < 64; o <<= 1) { u32 v = (u32)__shfl_up((int)inc, o); if (lane >= (u32)o) inc += v; }
      if (lane == 63) wtmp[wv] = inc;
      __syncthreads();
      u32 woff = 0; for (u32 w = 0; w < wv; w++) woff += wtmp[w];
      pref[t] = woff + inc - v0;
    }
    __syncthreads();
#pragma unroll
    for (int k = 0; k < 16; k++) {
      u32 i = c + (u32)k * 256u + t;
      if (i < c + m) {
        u32 s = (u32)(it[k] >> 24) & 255u;
        u32 p = pref[s] + atomicAdd(&cnt2[s], 1u);
        buf[p] = it[k];
      }
    }
    __syncthreads();
    for (u32 j = t; j < m; j += 256) {     // ascending-address write
      u64 pk = buf[j];
      wbf[(u32)((pk >> 16) & 0x3FFFFFFull)] = (u16)pk;
    }
    __syncthreads();
  }
}

typedef __bf16 bf16x8 __attribute__((ext_vector_type(8)));
typedef float f32x4 __attribute__((ext_vector_type(4)));

// GEMM2 (m97-structure): 128x128 tile, BK=64, global_load_lds width-16 with
// XOR-swizzle; XCD-paired mapping. KSPLIT=4 -> grid 512 = 2 blocks/CU fully
// resident (R9's 1024 @ 3/CU had a 256-block tail wave), 32 K-steps/block.
__global__ __launch_bounds__(256, 3) void k_gemm2(const u16* __restrict__ xbf,
                                                  const u16* __restrict__ wbf,
                                                  float* __restrict__ outp) {
  __shared__ u16 As[128 * 64];   // 16 KB, linear (row-major [128][64])
  __shared__ u16 Bs[128 * 64];   // 16 KB
  u32 i = blockIdx.x;
  u32 xcd = i & 7u, slot = i >> 3;
  u32 mi = slot & 1u, qq = slot >> 1;      // pair-slot within XCD (0..31)
  u32 pid = xcd * 32u + qq;                // (n,k) pair id, 0..255
  u32 kidx = pid >> 6;                     // 0..3
  u32 nb = pid & 63u;                      // 0..63
  u32 mrow = mi * 128u, nrow = nb * 128u;
  u32 kbase = kidx * 2048u;
  u32 tid = threadIdx.x;
  u32 lane = tid & 63, wv = tid >> 6;
  u32 l8 = lane & 7;             // chunk index within row (8x 16B chunks)
  u32 lr = lane >> 3;            // row within 8-row issue
  u32 wm = wv >> 1, wn = wv & 1;
  u32 r = lane & 15, q = lane >> 4;
  f32x4 acc[4][4];
#pragma unroll
  for (int a = 0; a < 4; a++)
#pragma unroll
    for (int b = 0; b < 4; b++) acc[a][b] = (f32x4){0.f, 0.f, 0.f, 0.f};

  for (u32 kb = kbase; kb < kbase + 2048u; kb += 64u) {
#pragma unroll
    for (int j = 0; j < 4; j++) {
      u32 g = wv * 4 + (u32)j;
      u32 row = g * 8 + lr;
      u32 sc = ((l8 ^ (row & 7u)) * 8u);   // pre-swizzled source col (bf16)
      const u16* ga = xbf + (u64)(mrow + row) * 8192 + kb + sc;
      __builtin_amdgcn_global_load_lds((const u32*)ga, (u32*)&As[g * 512u], 16, 0, 0);
      const u16* gb = wbf + (u64)(nrow + row) * 8192 + kb + sc;
      __builtin_amdgcn_global_load_lds((const u32*)gb, (u32*)&Bs[g * 512u], 16, 0, 0);
    }
    __syncthreads();
#pragma unroll
    for (int ks = 0; ks < 2; ks++) {
      bf16x8 a[4], b[4];
      u32 ch = (u32)(ks * 4) + q;          // logical chunk = K-slab col/8
#pragma unroll
      for (int mt = 0; mt < 4; mt++) {
        u32 row = wm * 64 + (u32)mt * 16 + r;
        a[mt] = *(bf16x8*)&As[row * 64 + ((ch ^ (r & 7u)) * 8u)];
      }
#pragma unroll
      for (int nt = 0; nt < 4; nt++) {
        u32 row = wn * 64 + (u32)nt * 16 + r;
        b[nt] = *(bf16x8*)&Bs[row * 64 + ((ch ^ (r & 7u)) * 8u)];
      }
#pragma unroll
      for (int mt = 0; mt < 4; mt++)
#pragma unroll
        for (int nt = 0; nt < 4; nt++)
          acc[mt][nt] = __builtin_amdgcn_mfma_f32_16x16x32_bf16(a[mt], b[nt], acc[mt][nt], 0, 0, 0);
    }
    __syncthreads();
  }
  float* op = outp + (u64)kidx * 2097152u;
  u32 quad = lane >> 4, col = lane & 15;
#pragma unroll
  for (int mt = 0; mt < 4; mt++)
#pragma unroll
    for (int nt = 0; nt < 4; nt++) {
      u32 n = nrow + wn * 64 + (u32)nt * 16 + col;
#pragma unroll
      for (int rg = 0; rg < 4; rg++) {
        u32 m = mrow + wm * 64 + (u32)mt * 16 + quad * 4 + (u32)rg;
        op[(u64)m * 8192 + n] = acc[mt][nt][rg];
      }
    }
}

// Reduce split-K partials -> out (fully writes out; no memset needed).
__global__ __launch_bounds__(256) void k_redout(const float* __restrict__ part,
                                                float* __restrict__ out) {
  u32 i = blockIdx.x * 256 + threadIdx.x;   // f32x4 group; 2M/4 = 524288 total
  float4 s = ((const float4*)part)[i];
#pragma unroll
  for (int k = 1; k < KSPLIT; k++) {
    float4 v = ((const float4*)(part + (u64)k * 2097152u))[i];
    s.x += v.x; s.y += v.y; s.z += v.z; s.w += v.w;
  }
  ((float4*)out)[i] = s;
}

// Fallback GEMM (reg-staged f32 W, atomics). Only if ws too small for wbf.
__global__ __launch_bounds__(256, 2) void k_gemm_fb(const u16* __restrict__ xbf,
                                                    const float* __restrict__ W,
                                                    float* __restrict__ out) {
  __shared__ u16 xs[256 * 72];
  __shared__ u16 wsm[64 * 72];
  u32 tid = threadIdx.x;
  u32 lane = tid & 63, wv = tid >> 6;
  u32 nt0 = blockIdx.x * 64;
  u32 kbase = blockIdx.y * 2048u;
  f32x4 acc[4][4];
#pragma unroll
  for (int i = 0; i < 4; i++)
#pragma unroll
    for (int j = 0; j < 4; j++) acc[i][j] = (f32x4){0.f, 0.f, 0.f, 0.f};
  for (u32 kb = kbase; kb < kbase + 2048u; kb += 64u) {
#pragma unroll
    for (int r8 = 0; r8 < 8; r8++) {
      u32 row = r8 * 32 + (tid >> 3);
      u32 kseg = (tid & 7) * 8;
      uint4 v = *(const uint4*)(xbf + (u64)row * 8192 + kb + kseg);
      *(uint4*)&xs[row * 72 + kseg] = v;
    }
#pragma unroll
    for (int rr = 0; rr < 4; rr++) {
      u32 f4 = rr * 256 + tid;
      u32 row = f4 >> 4;
      u32 kc = (f4 & 15) * 4;
      float4 v = *(const float4*)(W + (u64)(nt0 + row) * 8192 + kb + kc);
      ushort4 o; o.x = f2bf(v.x); o.y = f2bf(v.y); o.z = f2bf(v.z); o.w = f2bf(v.w);
      *(ushort4*)&wsm[row * 72 + kc] = o;
    }
    __syncthreads();
#pragma unroll
    for (int ks = 0; ks < 2; ks++) {
      bf16x8 a[4], b[4];
      u32 koff = ks * 32 + (lane >> 4) * 8;
      u32 rsel = lane & 15;
#pragma unroll
      for (int mt = 0; mt < 4; mt++) a[mt] = *(bf16x8*)&xs[(wv * 64 + mt * 16 + rsel) * 72 + koff];
#pragma unroll
      for (int nt = 0; nt < 4; nt++) b[nt] = *(bf16x8*)&wsm[(nt * 16 + rsel) * 72 + koff];
#pragma unroll
      for (int mt = 0; mt < 4; mt++)
#pragma unroll
        for (int nt = 0; nt < 4; nt++)
          acc[mt][nt] = __builtin_amdgcn_mfma_f32_16x16x32_bf16(a[mt], b[nt], acc[mt][nt], 0, 0, 0);
    }
    __syncthreads();
  }
  u32 quad = lane >> 4, col = lane & 15;
#pragma unroll
  for (int mt = 0; mt < 4; mt++)
#pragma unroll
    for (int nt = 0; nt < 4; nt++) {
      u32 n = nt0 + nt * 16 + col;
#pragma unroll
      for (int rg = 0; rg < 4; rg++) {
        u32 m = wv * 64 + mt * 16 + quad * 4 + rg;
        atomicAdd(&out[(u64)m * 8192 + n], acc[mt][nt][rg]);
      }
    }
}

extern "C" void kernel_launch(void* const* d_in, const int* in_sizes, int n_in,
                              void* d_out, int out_size, void* d_ws, size_t ws_size,
                              hipStream_t stream) {
  const float* x; float* W;
  if (in_sizes[0] == 2097152) { x = (const float*)d_in[0]; W = (float*)d_in[1]; }
  else                        { x = (const float*)d_in[1]; W = (float*)d_in[0]; }
  float* out = (float*)d_out;
  char* ws = (char*)d_ws;

  u32* colsum = (u32*)(ws + OFF_COLSUM);   // = gcur
  u32* sbase  = (u32*)(ws + OFF_SBASE);
  Scalars* sc = (Scalars*)(ws + OFF_SC);
  u32* segcnt = (u32*)(ws + OFF_SEGCNT);
  u16* xbf    = (u16*)(ws + OFF_XBF);
  u32* segs   = (u32*)(ws + OFF_SEGS);
  u32* routed = (u32*)(ws + OFF_ROUTED);
  u16* wbf    = (u16*)(ws + OFF_WBF);
  float* outp = (float*)(ws + OFF_OUTP);
  u64* flipflat = (u64*)(ws + OFF_FLIPF);
  u64* fb1      = (u64*)(ws + OFF_FB1);
  u32* bcur     = (u32*)(ws + OFF_BCUR);

  bool t3 = (ws_size >= (size_t)WS_NEED_T3);
  bool t1 = (ws_size >= (size_t)WS_NEED_WBF);

  // PARTITIONABLE split of key(42): key[i] = threefry(k=(0,42), counter=(0,i))
  u32 a0, a1, b0, b1;
  tf2x32(0u, 42u, 0u, 0u, a0, a1);   // ks -> uniform scores
  tf2x32(0u, 42u, 0u, 1u, b0, b1);   // kv -> normal vals

  hipMemsetAsync(sc, 0, sizeof(Scalars), stream);
  hipMemsetAsync(colsum, 0, 2048 * sizeof(u32), stream);
  if (t3) hipMemsetAsync(bcur, 0, NBKT * sizeof(u32), stream);

  u32 dowbf = t1 ? 1u : 0u;
  k_pass1w<<<2048, 256, 0, stream>>>(W, wbf, x, xbf, sc, segcnt, segs, a0, a1, dowbf);
  k_route<<<RBLK, 256, 0, stream>>>(segs, segcnt, colsum, routed, a0, a1);
  k_scan<<<1, 256, 0, stream>>>(colsum, sc, sbase);
  if (t3) {
    k_rank<2><<<NSUP, 256, 0, stream>>>(W, wbf, flipflat, colsum, sbase, routed, sc, a0, a1, b0, b1);
    k_part<<<256, 256, 0, stream>>>(flipflat, sc, fb1, bcur);
    k_apply<<<NBKT, 256, 0, stream>>>(fb1, bcur, wbf);
    k_gemm2<<<512, 256, 0, stream>>>(xbf, wbf, outp);
    k_redout<<<2048, 256, 0, stream>>>(outp, out);
  } else if (t1) {
    k_rank<1><<<NSUP, 256, 0, stream>>>(W, wbf, flipflat, colsum, sbase, routed, sc, a0, a1, b0, b1);
    k_gemm2<<<512, 256, 0, stream>>>(xbf, wbf, outp);
    k_redout<<<2048, 256, 0, stream>>>(outp, out);
  } else {
    k_rank<0><<<NSUP, 256, 0, stream>>>(W, wbf, flipflat, colsum, sbase, routed, sc, a0, a1, b0, b1);
    hipMemsetAsync(out, 0, (size_t)out_size * 4, stream);
    dim3 g(128, 4);
    k_gemm_fb<<<g, 256, 0, stream>>>(xbf, W, out);
  }
}

// Round 11
// 942.621 us; speedup vs baseline: 1.1391x; 1.1391x over previous
//
#include <hip/hip_runtime.h>

typedef unsigned int u32;
typedef unsigned long long u64;
typedef unsigned short u16;

#define NTOT   67108864u    // 8192*8192 = 2^26
#define T0P    7543296u     // candidate threshold = PBASE*512; true cutoff 7549747 +- 324 (20 sigma)
#define PBASE  14733u       // T0P >> 9
#define NSUP   1651u        // supers of 512 fine bins, covering [T0P, 2^23)
#define NWSEG  4096u        // per-wave segments (1024 pass1 blocks x 4 waves)
#define WCAP   2176u        // per-wave cap: mean 1487, sigma 36.8 -> +18.7 sigma
#define RBLK   512u         // k_route blocks (2 blocks/CU)
#define SEGPB  8            // segs per route block (RBLK*SEGPB = NWSEG)
#define RCAP   4352u        // per-super cap: mean 3689, sigma 61 -> +10.9 sigma
#define KSPLIT 4            // gemm2 split-K: grid 512 = 2 blocks/CU, no residency tail

struct Scalars {
  double sumW;
  double sumW2;
  u64 npruned;
  u64 nflip;
  float stdf;
  float pad;
};

// ---- ws layout (bytes) ---- (R9 layout)
#define OFF_COLSUM 0ull          // gcur/colsum: 2048 u32 = 8192
#define OFF_SBASE  8192ull       // 2048 u32 -> ends 16384
#define OFF_SC     16384ull      // 128 B
#define OFF_SEGCNT 16512ull      // 4096 u32 -> ends 32896
#define OFF_XBF    33024ull      // 4,194,304 -> ends 4,227,328
#define OFF_SEGS   4227328ull    // 35,651,584 -> ends 39,878,912
#define OFF_ROUTED 39878912ull   // 2048*4352*4 = 35,651,584 -> ends 75,530,496
#define OFF_WBF    75530496ull   // bf16 W copy: 134,217,728 -> ends 209,748,224
#define WS_NEED_WBF 209748224ull
// gemm2 partials REUSE segs+routed (dead after k_rank): 4 x 8 MB = 32 MB ok
#define OFF_OUTP   OFF_SEGS

// JAX Threefry-2x32, 20 rounds — verified vs known-answer vector
__host__ __device__ inline void tf2x32(u32 k0, u32 k1, u32 x0, u32 x1, u32& y0, u32& y1) {
  u32 ks2 = k0 ^ k1 ^ 0x1BD11BDAu;
  x0 += k0; x1 += k1;
#define TFR(r) { x0 += x1; x1 = (x1 << (r)) | (x1 >> (32 - (r))); x1 ^= x0; }
  TFR(13) TFR(15) TFR(26) TFR(6)  x0 += k1;  x1 += ks2 + 1u;
  TFR(17) TFR(29) TFR(16) TFR(24) x0 += ks2; x1 += k0 + 2u;
  TFR(13) TFR(15) TFR(26) TFR(6)  x0 += k0;  x1 += k1 + 3u;
  TFR(17) TFR(29) TFR(16) TFR(24) x0 += k1;  x1 += ks2 + 4u;
  TFR(13) TFR(15) TFR(26) TFR(6)  x0 += ks2; x1 += k0 + 5u;
#undef TFR
  y0 = x0; y1 = x1;
}

// Partitionable-mode bits for element i: counter (0, i), bits = y0 ^ y1
__device__ inline u32 jax_bits32(u32 k0, u32 k1, u32 i) {
  u32 y0, y1; tf2x32(k0, k1, 0u, i, y0, y1);
  return y0 ^ y1;
}

__device__ inline u16 f2bf(float f) {
  union { float f; u32 u; } c; c.f = f;
  u32 r = ((c.u >> 16) & 1u) + 0x7FFFu;   // RNE
  return (u16)((c.u + r) >> 16);
}

// XLA ErfInv (f32, Giles)
__device__ inline float erfinv32(float x) {
  float w = -log1pf(-x * x);
  float p;
  if (w < 5.0f) {
    w -= 2.5f;
    p = 2.81022636e-08f;
    p = fmaf(p, w, 3.43273939e-07f);
    p = fmaf(p, w, -3.5233877e-06f);
    p = fmaf(p, w, -4.39150654e-06f);
    p = fmaf(p, w, 0.00021858087f);
    p = fmaf(p, w, -0.00125372503f);
    p = fmaf(p, w, -0.00417768164f);
    p = fmaf(p, w, 0.246640727f);
    p = fmaf(p, w, 1.50140941f);
  } else {
    w = sqrtf(w) - 3.0f;
    p = -0.000200214257f;
    p = fmaf(p, w, 0.000100950558f);
    p = fmaf(p, w, 0.00134934322f);
    p = fmaf(p, w, -0.00367342844f);
    p = fmaf(p, w, 0.00573950773f);
    p = fmaf(p, w, -0.0076224613f);
    p = fmaf(p, w, 0.00943887047f);
    p = fmaf(p, w, 1.00167406f);
    p = fmaf(p, w, 2.83297682f);
  }
  return p * x;
}

// Fused pass1 + wconv + xconv heterogeneous grid. pass1 now 8 elems/iter
// (2x float4, 8 threefry chains) with the per-ITERATION shfl-scan kept —
// halves scan count vs R9's 4-elem (R3's 8-elem failure was confounded with
// per-ELEMENT ballot+mbcnt, which serialized 8 exec-mask ops per iter).
__global__ __launch_bounds__(256) void k_pass1w(const float* __restrict__ W,
                                                u16* __restrict__ wbf,
                                                const float* __restrict__ x,
                                                u16* __restrict__ xbf,
                                                Scalars* sc, u32* segcnt, u32* segs,
                                                u32 uk0, u32 uk1, u32 dowbf) {
  u32 t = threadIdx.x;
  u32 bid = blockIdx.x;
  if (bid < 1024u) {
    u32 gid = bid * 256 + t;
    u32 lane = t & 63;
    u32 wid = gid >> 6;
    u32* wseg = segs + (u64)wid * WCAP;
    u32 wbase = 0;                     // wave-uniform cursor, kept in registers
    float sf = 0.f, sf2 = 0.f; u32 cnt = 0;
    const u32 stride8 = 1024u * 256u * 8u;
    for (u32 b8 = gid * 8; b8 < NTOT; b8 += stride8) {
      float4 wa = *(const float4*)(W + b8);
      float4 wb = *(const float4*)(W + b8 + 4);
      u32 sb[8];
#pragma unroll
      for (int e = 0; e < 8; e++) sb[e] = jax_bits32(uk0, uk1, b8 + (u32)e) >> 9;
      float we[8] = {wa.x, wa.y, wa.z, wa.w, wb.x, wb.y, wb.z, wb.w};
      u32 cand[8]; u32 nc = 0;
#pragma unroll
      for (int e = 0; e < 8; e++) {
        float w = we[e];
        sf += w;
        sf2 = fmaf(w, w, sf2);
        bool pr = (w == 0.0f);
        cnt += pr ? 1u : 0u;
        if (pr && sb[e] >= T0P) { cand[nc] = b8 + (u32)e; nc++; }
      }
      u32 inc = nc;                    // wave inclusive scan of per-lane counts
#pragma unroll
      for (int o = 1; o < 64; o <<= 1) { u32 v = (u32)__shfl_up((int)inc, o); if (lane >= (u32)o) inc += v; }
      u32 tot = (u32)__shfl((int)inc, 63);
      u32 pos = wbase + inc - nc;
      for (u32 k2 = 0; k2 < nc; k2++)
        if (pos + k2 < WCAP) wseg[pos + k2] = cand[k2];
      wbase += tot;
    }
    double s = (double)sf, s2 = (double)sf2;
    for (int o = 32; o > 0; o >>= 1) {
      s += __shfl_down(s, o); s2 += __shfl_down(s2, o); cnt += __shfl_down(cnt, o);
    }
    if (lane == 0) {
      atomicAdd(&sc->sumW, s);
      atomicAdd(&sc->sumW2, s2);
      atomicAdd(&sc->npruned, (u64)cnt);
      segcnt[wid] = (wbase > WCAP) ? WCAP : wbase;
    }
  } else if (bid < 1984u) {
    if (!dowbf) return;
    u32 i0 = (bid - 1024u) * 256 + t;
    const u32 stride = 960u * 256u;
    for (u32 g = i0; g < NTOT / 8u; g += stride) {
      const float4* p = (const float4*)(W + (u64)g * 8);
      float4 a = p[0], b = p[1];
      uint4 o;
      o.x = (u32)f2bf(a.x) | ((u32)f2bf(a.y) << 16);
      o.y = (u32)f2bf(a.z) | ((u32)f2bf(a.w) << 16);
      o.z = (u32)f2bf(b.x) | ((u32)f2bf(b.y) << 16);
      o.w = (u32)f2bf(b.z) | ((u32)f2bf(b.w) << 16);
      *(uint4*)(wbf + (u64)g * 8) = o;
    }
  } else {
    u32 i0 = (bid - 1984u) * 256 + t;
    const u32 stride = 64u * 256u;
    for (u32 g = i0; g < 524288u; g += stride) {
      float4 v = ((const float4*)x)[g];
      ushort4 o; o.x = f2bf(v.x); o.y = f2bf(v.y); o.z = f2bf(v.z); o.w = f2bf(v.w);
      ((ushort4*)xbf)[g] = o;
    }
  }
}

// Single-pass route: LDS count -> global reserve -> scatter into fixed-stride
// routed[sup*RCAP] (R9, verified).
__global__ __launch_bounds__(256) void k_route(const u32* __restrict__ segs,
                                               const u32* __restrict__ segcnt,
                                               u32* gcur, u32* routed,
                                               u32 uk0, u32 uk1) {
  __shared__ u32 lhist[2048];
  __shared__ u32 lbase[2048];
  u32 t = threadIdx.x;
  for (u32 j = t; j < 2048; j += 256) lhist[j] = 0;
  __syncthreads();
#pragma unroll 1
  for (int sg = 0; sg < SEGPB; sg++) {
    u32 wid = blockIdx.x * SEGPB + sg;
    u32 n = segcnt[wid]; if (n > WCAP) n = WCAP;
    const u32* sp = segs + (u64)wid * WCAP;
    for (u32 i = t; i < n; i += 256)
      atomicAdd(&lhist[(jax_bits32(uk0, uk1, sp[i]) >> 18) - PBASE], 1u);
  }
  __syncthreads();
  for (u32 j = t; j < 2048; j += 256) {
    u32 c = lhist[j];
    lbase[j] = c ? atomicAdd(&gcur[j], c) : 0u;
    lhist[j] = 0;
  }
  __syncthreads();
#pragma unroll 1
  for (int sg = 0; sg < SEGPB; sg++) {
    u32 wid = blockIdx.x * SEGPB + sg;
    u32 n = segcnt[wid]; if (n > WCAP) n = WCAP;
    const u32* sp = segs + (u64)wid * WCAP;
    for (u32 i = t; i < n; i += 256) {
      u32 idx = sp[i];
      u32 sup = (jax_bits32(uk0, uk1, idx) >> 18) - PBASE;
      u32 pos = lbase[sup] + atomicAdd(&lhist[sup], 1u);
      if (pos < RCAP) routed[(u64)sup * RCAP + pos] = idx;
    }
  }
}

// Scalars + 2048-wide suffix-exclusive scan (sbase = rank base per super).
__global__ __launch_bounds__(256) void k_scan(const u32* __restrict__ colsum, Scalars* sc,
                                              u32* sbase) {
  __shared__ u32 h[2048];
  __shared__ u32 wtmp[4];
  u32 t = threadIdx.x, lane = t & 63, wv = t >> 6;
  for (u32 j = t; j < 2048; j += 256) h[j] = colsum[j];
  __syncthreads();
  u32 a[8]; u32 s8 = 0;
#pragma unroll
  for (int k = 0; k < 8; k++) { a[k] = h[2047 - (t * 8 + k)]; s8 += a[k]; }
  u32 inc = s8;
#pragma unroll
  for (int o = 1; o < 64; o <<= 1) { u32 v = (u32)__shfl_up((int)inc, o); if (lane >= (u32)o) inc += v; }
  if (lane == 63) wtmp[wv] = inc;
  __syncthreads();
  u32 woff = 0; for (u32 w = 0; w < wv; w++) woff += wtmp[w];
  u32 base = woff + inc - s8;
#pragma unroll
  for (int k = 0; k < 8; k++) { sbase[2047 - (t * 8 + k)] = base; base += a[k]; }
  if (t == 0) {
    double nk = (double)NTOT - (double)sc->npruned;
    double mean = sc->sumW / nk;
    double var = (sc->sumW2 - 2.0 * mean * sc->sumW + nk * mean * mean) / (nk - 1.0);
    sc->stdf = (float)sqrt(var);
    u64 nfi = (u64)(0.1 * (double)sc->npruned);
    if (nfi < 1) nfi = 1;
    sc->nflip = nfi;
  }
}

// 512-bin suffix-exclusive scan (256 threads, 2 bins each)
__device__ inline void suf512(const u32* cnt, u32* suf, u32* wtmp) {
  u32 t = threadIdx.x, lane = t & 63, wv = t >> 6;
  u32 a0 = cnt[511 - t * 2], a1 = cnt[510 - t * 2];
  u32 s = a0 + a1;
  u32 inc = s;
#pragma unroll
  for (int o = 1; o < 64; o <<= 1) { u32 v = (u32)__shfl_up((int)inc, o); if (lane >= (u32)o) inc += v; }
  if (lane == 63) wtmp[wv] = inc;
  __syncthreads();
  u32 woff = 0;
  for (u32 w = 0; w < wv; w++) woff += wtmp[w];
  u32 base = woff + inc - s;
  suf[511 - t * 2] = base;
  suf[510 - t * 2] = base + a0;
  __syncthreads();
}

// Rank: one block per 512-bin super, fixed-stride routed. MODE 1: direct bf16
// scatter into wbf (measured cheaper than every sort-based alternative:
// R6 +160us, R10 +109us). MODE 0: fp32 into W (fallback).
template<int MODE>
__global__ __launch_bounds__(256) void k_rank(float* __restrict__ W,
                                              u16* __restrict__ wbf,
                                              const u32* __restrict__ colsum,
                                              const u32* __restrict__ sbase,
                                              const u32* __restrict__ routed,
                                              const Scalars* __restrict__ sc,
                                              u32 uk0, u32 uk1, u32 vk0, u32 vk1) {
  u32 p = blockIdx.x;
  u32 n = colsum[p]; if (n == 0) return;
  if (n > RCAP) n = RCAP;
  u64 nflip = sc->nflip;
  u32 rbase = sbase[p];
  if ((u64)rbase >= nflip) return;
  __shared__ u32 sIdx[RCAP];
  __shared__ u16 sFine[RCAP];
  __shared__ u32 pIdx[RCAP];
  __shared__ u32 hist[512], gbase[512], cur[512], wtmp[4];
  u32 t = threadIdx.x;
  for (u32 j = t; j < 512; j += 256) hist[j] = 0;
  __syncthreads();
  const u32* src = routed + (u64)p * RCAP;
  for (u32 i = t; i < n; i += 256) {
    u32 idx = src[i];
    u32 f = (jax_bits32(uk0, uk1, idx) >> 9) & 511u;
    sIdx[i] = idx;
    sFine[i] = (u16)f;
    atomicAdd(&hist[f], 1u);
  }
  __syncthreads();
  suf512(hist, gbase, wtmp);         // gbase[f] = # members with fine > f
  for (u32 j = t; j < 512; j += 256) cur[j] = gbase[j];
  __syncthreads();
  for (u32 i = t; i < n; i += 256) {
    u32 pos = atomicAdd(&cur[sFine[i]], 1u);
    pIdx[pos] = sIdx[i];
  }
  __syncthreads();
  float stdf = sc->stdf;
  for (u32 i = t; i < n; i += 256) {
    u32 f = sFine[i];
    u32 g0 = gbase[f], g1 = g0 + hist[f];
    u32 v = sIdx[i];
    u32 ord = 0;
    for (u32 q = g0; q < g1; q++) ord += (pIdx[q] < v) ? 1u : 0u;
    u64 rank = (u64)rbase + g0 + ord;
    if (rank >= nflip) continue;
    u32 bits = jax_bits32(vk0, vk1, (u32)rank);
    union { u32 u; float fl; } cv; cv.u = 0x3F800000u | (bits >> 9);
    float fu = cv.fl - 1.0f;               // uniform [0,1)
    const float lo = -0.99999994f;         // nextafter(-1,0); (1-lo) rounds to 2.0f
    float u2 = fmaxf(lo, fu * 2.0f + lo);  // uniform [lo, 1)
    float nrm = 1.41421354f * erfinv32(u2);
    float val = (nrm * stdf) * 0.1f;
    if (MODE == 1) wbf[v] = f2bf(val);
    else           W[v] = val;
  }
}

typedef __bf16 bf16x8 __attribute__((ext_vector_type(8)));
typedef float f32x4 __attribute__((ext_vector_type(4)));

// GEMM2 (m97-structure): 128x128 tile, BK=64, global_load_lds width-16 with
// XOR-swizzle; XCD-paired mapping. KSPLIT=4 -> grid 512 = 2 blocks/CU fully
// resident (no residency tail), 32 K-steps/block.
__global__ __launch_bounds__(256, 3) void k_gemm2(const u16* __restrict__ xbf,
                                                  const u16* __restrict__ wbf,
                                                  float* __restrict__ outp) {
  __shared__ u16 As[128 * 64];   // 16 KB, linear (row-major [128][64])
  __shared__ u16 Bs[128 * 64];   // 16 KB
  u32 i = blockIdx.x;
  u32 xcd = i & 7u, slot = i >> 3;
  u32 mi = slot & 1u, qq = slot >> 1;      // pair-slot within XCD (0..31)
  u32 pid = xcd * 32u + qq;                // (n,k) pair id, 0..255
  u32 kidx = pid >> 6;                     // 0..3
  u32 nb = pid & 63u;                      // 0..63
  u32 mrow = mi * 128u, nrow = nb * 128u;
  u32 kbase = kidx * 2048u;
  u32 tid = threadIdx.x;
  u32 lane = tid & 63, wv = tid >> 6;
  u32 l8 = lane & 7;             // chunk index within row (8x 16B chunks)
  u32 lr = lane >> 3;            // row within 8-row issue
  u32 wm = wv >> 1, wn = wv & 1;
  u32 r = lane & 15, q = lane >> 4;
  f32x4 acc[4][4];
#pragma unroll
  for (int a = 0; a < 4; a++)
#pragma unroll
    for (int b = 0; b < 4; b++) acc[a][b] = (f32x4){0.f, 0.f, 0.f, 0.f};

  for (u32 kb = kbase; kb < kbase + 2048u; kb += 64u) {
#pragma unroll
    for (int j = 0; j < 4; j++) {
      u32 g = wv * 4 + (u32)j;
      u32 row = g * 8 + lr;
      u32 sc = ((l8 ^ (row & 7u)) * 8u);   // pre-swizzled source col (bf16)
      const u16* ga = xbf + (u64)(mrow + row) * 8192 + kb + sc;
      __builtin_amdgcn_global_load_lds((const u32*)ga, (u32*)&As[g * 512u], 16, 0, 0);
      const u16* gb = wbf + (u64)(nrow + row) * 8192 + kb + sc;
      __builtin_amdgcn_global_load_lds((const u32*)gb, (u32*)&Bs[g * 512u], 16, 0, 0);
    }
    __syncthreads();
#pragma unroll
    for (int ks = 0; ks < 2; ks++) {
      bf16x8 a[4], b[4];
      u32 ch = (u32)(ks * 4) + q;          // logical chunk = K-slab col/8
#pragma unroll
      for (int mt = 0; mt < 4; mt++) {
        u32 row = wm * 64 + (u32)mt * 16 + r;
        a[mt] = *(bf16x8*)&As[row * 64 + ((ch ^ (r & 7u)) * 8u)];
      }
#pragma unroll
      for (int nt = 0; nt < 4; nt++) {
        u32 row = wn * 64 + (u32)nt * 16 + r;
        b[nt] = *(bf16x8*)&Bs[row * 64 + ((ch ^ (r & 7u)) * 8u)];
      }
#pragma unroll
      for (int mt = 0; mt < 4; mt++)
#pragma unroll
        for (int nt = 0; nt < 4; nt++)
          acc[mt][nt] = __builtin_amdgcn_mfma_f32_16x16x32_bf16(a[mt], b[nt], acc[mt][nt], 0, 0, 0);
    }
    __syncthreads();
  }
  float* op = outp + (u64)kidx * 2097152u;
  u32 quad = lane >> 4, col = lane & 15;
#pragma unroll
  for (int mt = 0; mt < 4; mt++)
#pragma unroll
    for (int nt = 0; nt < 4; nt++) {
      u32 n = nrow + wn * 64 + (u32)nt * 16 + col;
#pragma unroll
      for (int rg = 0; rg < 4; rg++) {
        u32 m = mrow + wm * 64 + (u32)mt * 16 + quad * 4 + (u32)rg;
        op[(u64)m * 8192 + n] = acc[mt][nt][rg];
      }
    }
}

// Reduce split-K partials -> out (fully writes out; no memset needed).
__global__ __launch_bounds__(256) void k_redout(const float* __restrict__ part,
                                                float* __restrict__ out) {
  u32 i = blockIdx.x * 256 + threadIdx.x;   // f32x4 group; 2M/4 = 524288 total
  float4 s = ((const float4*)part)[i];
#pragma unroll
  for (int k = 1; k < KSPLIT; k++) {
    float4 v = ((const float4*)(part + (u64)k * 2097152u))[i];
    s.x += v.x; s.y += v.y; s.z += v.z; s.w += v.w;
  }
  ((float4*)out)[i] = s;
}

// Fallback GEMM (reg-staged f32 W, atomics). Only if ws too small for wbf.
__global__ __launch_bounds__(256, 2) void k_gemm_fb(const u16* __restrict__ xbf,
                                                    const float* __restrict__ W,
                                                    float* __restrict__ out) {
  __shared__ u16 xs[256 * 72];
  __shared__ u16 wsm[64 * 72];
  u32 tid = threadIdx.x;
  u32 lane = tid & 63, wv = tid >> 6;
  u32 nt0 = blockIdx.x * 64;
  u32 kbase = blockIdx.y * 2048u;
  f32x4 acc[4][4];
#pragma unroll
  for (int i = 0; i < 4; i++)
#pragma unroll
    for (int j = 0; j < 4; j++) acc[i][j] = (f32x4){0.f, 0.f, 0.f, 0.f};
  for (u32 kb = kbase; kb < kbase + 2048u; kb += 64u) {
#pragma unroll
    for (int r8 = 0; r8 < 8; r8++) {
      u32 row = r8 * 32 + (tid >> 3);
      u32 kseg = (tid & 7) * 8;
      uint4 v = *(const uint4*)(xbf + (u64)row * 8192 + kb + kseg);
      *(uint4*)&xs[row * 72 + kseg] = v;
    }
#pragma unroll
    for (int rr = 0; rr < 4; rr++) {
      u32 f4 = rr * 256 + tid;
      u32 row = f4 >> 4;
      u32 kc = (f4 & 15) * 4;
      float4 v = *(const float4*)(W + (u64)(nt0 + row) * 8192 + kb + kc);
      ushort4 o; o.x = f2bf(v.x); o.y = f2bf(v.y); o.z = f2bf(v.z); o.w = f2bf(v.w);
      *(ushort4*)&wsm[row * 72 + kc] = o;
    }
    __syncthreads();
#pragma unroll
    for (int ks = 0; ks < 2; ks++) {
      bf16x8 a[4], b[4];
      u32 koff = ks * 32 + (lane >> 4) * 8;
      u32 rsel = lane & 15;
#pragma unroll
      for (int mt = 0; mt < 4; mt++) a[mt] = *(bf16x8*)&xs[(wv * 64 + mt * 16 + rsel) * 72 + koff];
#pragma unroll
      for (int nt = 0; nt < 4; nt++) b[nt] = *(bf16x8*)&wsm[(nt * 16 + rsel) * 72 + koff];
#pragma unroll
      for (int mt = 0; mt < 4; mt++)
#pragma unroll
        for (int nt = 0; nt < 4; nt++)
          acc[mt][nt] = __builtin_amdgcn_mfma_f32_16x16x32_bf16(a[mt], b[nt], acc[mt][nt], 0, 0, 0);
    }
    __syncthreads();
  }
  u32 quad = lane >> 4, col = lane & 15;
#pragma unroll
  for (int mt = 0; mt < 4; mt++)
#pragma unroll
    for (int nt = 0; nt < 4; nt++) {
      u32 n = nt0 + nt * 16 + col;
#pragma unroll
      for (int rg = 0; rg < 4; rg++) {
        u32 m = wv * 64 + mt * 16 + quad * 4 + rg;
        atomicAdd(&out[(u64)m * 8192 + n], acc[mt][nt][rg]);
      }
    }
}

extern "C" void kernel_launch(void* const* d_in, const int* in_sizes, int n_in,
                              void* d_out, int out_size, void* d_ws, size_t ws_size,
                              hipStream_t stream) {
  const float* x; float* W;
  if (in_sizes[0] == 2097152) { x = (const float*)d_in[0]; W = (float*)d_in[1]; }
  else                        { x = (const float*)d_in[1]; W = (float*)d_in[0]; }
  float* out = (float*)d_out;
  char* ws = (char*)d_ws;

  u32* colsum = (u32*)(ws + OFF_COLSUM);   // = gcur
  u32* sbase  = (u32*)(ws + OFF_SBASE);
  Scalars* sc = (Scalars*)(ws + OFF_SC);
  u32* segcnt = (u32*)(ws + OFF_SEGCNT);
  u16* xbf    = (u16*)(ws + OFF_XBF);
  u32* segs   = (u32*)(ws + OFF_SEGS);
  u32* routed = (u32*)(ws + OFF_ROUTED);
  u16* wbf    = (u16*)(ws + OFF_WBF);
  float* outp = (float*)(ws + OFF_OUTP);

  bool t1 = (ws_size >= (size_t)WS_NEED_WBF);

  // PARTITIONABLE split of key(42): key[i] = threefry(k=(0,42), counter=(0,i))
  u32 a0, a1, b0, b1;
  tf2x32(0u, 42u, 0u, 0u, a0, a1);   // ks -> uniform scores
  tf2x32(0u, 42u, 0u, 1u, b0, b1);   // kv -> normal vals

  hipMemsetAsync(sc, 0, sizeof(Scalars), stream);
  hipMemsetAsync(colsum, 0, 2048 * sizeof(u32), stream);

  u32 dowbf = t1 ? 1u : 0u;
  k_pass1w<<<2048, 256, 0, stream>>>(W, wbf, x, xbf, sc, segcnt, segs, a0, a1, dowbf);
  k_route<<<RBLK, 256, 0, stream>>>(segs, segcnt, colsum, routed, a0, a1);
  k_scan<<<1, 256, 0, stream>>>(colsum, sc, sbase);
  if (t1) {
    k_rank<1><<<NSUP, 256, 0, stream>>>(W, wbf, colsum, sbase, routed, sc, a0, a1, b0, b1);
    k_gemm2<<<512, 256, 0, stream>>>(xbf, wbf, outp);
    k_redout<<<2048, 256, 0, stream>>>(outp, out);
  } else {
    k_rank<0><<<NSUP, 256, 0, stream>>>(W, wbf, colsum, sbase, routed, sc, a0, a1, b0, b1);
    hipMemsetAsync(out, 0, (size_t)out_size * 4, stream);
    dim3 g(128, 4);
    k_gemm_fb<<<g, 256, 0, stream>>>(xbf, W, out);
  }
}